// Round 1
// baseline (1827.926 us; speedup 1.0000x reference)
//
#include <hip/hip_runtime.h>

#define NSTATE 512
#define TT     20000   // t_eval length (output rows)
#define NSTEP  20000   // padded step count (19999 real + 1 zero step)
#define SCH    16      // steps per chunk
#define CCH    1250    // chunks (16*1250 = 20000)
#define NDATA  2000    // Tout length
#define H_DT   30.0f

// workspace layout in floats
static constexpr size_t OFF_H     = 0;
static constexpr size_t OFF_M     = OFF_H  + 512*512;
static constexpr size_t OFF_T1    = OFF_M  + 512*512;
static constexpr size_t OFF_T2    = OFF_T1 + 512*512;
static constexpr size_t OFF_Q0    = OFF_T2 + 512*512;
static constexpr size_t OFF_Q1    = OFF_Q0 + 512*512;
static constexpr size_t OFF_VEC   = OFF_Q1 + 512*512;    // v,w1,w2,w3 @0/512/1024/1536; c,u1,u2,u3 @2048..; g @4096
static constexpr size_t OFF_ALPHA = OFF_VEC + 16*512;    // NSTEP*8
static constexpr size_t OFF_YA    = OFF_ALPHA + (size_t)NSTEP*8;
static constexpr size_t OFF_YB    = OFF_YA + (size_t)CCH*512;
static constexpr size_t OFF_SA    = OFF_YB + (size_t)CCH*512;        // (CCH+1) rows
static constexpr size_t OFF_SB    = OFF_SA + (size_t)(CCH+1)*512;

__global__ void k_scaleH(const float* __restrict__ A, float* __restrict__ Hm) {
    int i = blockIdx.x * 256 + threadIdx.x;
    if (i < 512 * 512) Hm[i] = H_DT * A[i];
}

__global__ void k_prep_vc(const float* __restrict__ B, const float* __restrict__ Q,
                          float* __restrict__ vec) {
    int i = threadIdx.x;  // 512 threads
    float v = B[i * 9];
    float c = 0.f;
    #pragma unroll
    for (int j = 0; j < 8; j++) c += B[i * 9 + 1 + j] * Q[j];
    vec[i] = v;
    vec[2048 + i] = c;
}

// y1 = H x1, y2 = H x2  (grid 2 x 256 threads, one row per thread)
__global__ void k_matvec2(const float* __restrict__ Hm, const float* __restrict__ x1,
                          const float* __restrict__ x2, float* __restrict__ y1,
                          float* __restrict__ y2) {
    __shared__ float s1[512], s2[512];
    int t = threadIdx.x;
    int r = blockIdx.x * 256 + t;
    s1[t] = x1[t]; s1[t + 256] = x1[t + 256];
    s2[t] = x2[t]; s2[t + 256] = x2[t + 256];
    __syncthreads();
    float a1 = 0.f, a2 = 0.f;
    const float* row = Hm + (size_t)r * 512;
    for (int k = 0; k < 512; k++) { float h = row[k]; a1 += h * s1[k]; a2 += h * s2[k]; }
    y1[r] = a1; y2[r] = a2;
}

__global__ void k_gfin(float* __restrict__ vec) {
    int i = threadIdx.x;  // 512
    vec[4096 + i] = H_DT * (vec[2048 + i] + 0.5f * vec[2560 + i] +
                            (1.f / 6.f) * vec[3072 + i] + (1.f / 24.f) * vec[3584 + i]);
}

// Z = P * Q  (NN, 512x512x512)
__global__ __launch_bounds__(256) void k_mm_nn(const float* __restrict__ P,
                                               const float* __restrict__ Qm,
                                               float* __restrict__ Z) {
    __shared__ float Ps[32][33], Qs[32][33];
    int t = threadIdx.x;
    int r = t >> 3, c4 = (t & 7) * 4;
    int rb = blockIdx.y * 32, cb = blockIdx.x * 32;
    float4 acc = {0.f, 0.f, 0.f, 0.f};
    for (int kt = 0; kt < 512; kt += 32) {
        float4 pv = *(const float4*)(P + (size_t)(rb + r) * 512 + kt + c4);
        Ps[r][c4] = pv.x; Ps[r][c4 + 1] = pv.y; Ps[r][c4 + 2] = pv.z; Ps[r][c4 + 3] = pv.w;
        float4 qv = *(const float4*)(Qm + (size_t)(kt + r) * 512 + cb + c4);
        Qs[r][c4] = qv.x; Qs[r][c4 + 1] = qv.y; Qs[r][c4 + 2] = qv.z; Qs[r][c4 + 3] = qv.w;
        __syncthreads();
        #pragma unroll
        for (int k = 0; k < 32; k++) {
            float p = Ps[r][k];
            acc.x += p * Qs[k][c4];     acc.y += p * Qs[k][c4 + 1];
            acc.z += p * Qs[k][c4 + 2]; acc.w += p * Qs[k][c4 + 3];
        }
        __syncthreads();
    }
    *(float4*)(Z + (size_t)(rb + r) * 512 + cb + c4) = acc;
}

__global__ void k_combineM(const float* __restrict__ Hm, const float* __restrict__ H2,
                           const float* __restrict__ H3, const float* __restrict__ H4,
                           float* __restrict__ Mm) {
    int i = blockIdx.x * 256 + threadIdx.x;
    if (i >= 512 * 512) return;
    int r = i >> 9, c = i & 511;
    float m = Hm[i] + 0.5f * H2[i] + (1.f / 6.f) * H3[i] + (1.f / 24.f) * H4[i];
    if (r == c) m += 1.f;
    Mm[i] = m;
}

__device__ __forceinline__ float interp1(float t, const float* __restrict__ xp,
                                         const float* __restrict__ fp) {
    if (t <= xp[0]) return fp[0];
    if (t >= xp[NDATA - 1]) return fp[NDATA - 1];
    int lo = 0, hi = NDATA - 1;
    while (hi - lo > 1) { int mid = (lo + hi) >> 1; if (xp[mid] <= t) lo = mid; else hi = mid; }
    float x0 = xp[lo], x1 = xp[lo + 1];
    return fp[lo] + (fp[lo + 1] - fp[lo]) * (t - x0) / (x1 - x0);
}

__global__ void k_alphas(const float* __restrict__ te, const float* __restrict__ Tt,
                         const float* __restrict__ Tv, float* __restrict__ alpha) {
    int n = blockIdx.x * 256 + threadIdx.x;
    if (n >= NSTEP) return;
    float* a = alpha + (size_t)n * 8;
    if (n == NSTEP - 1) { a[0] = a[1] = a[2] = a[3] = a[4] = 0.f; return; }  // padding step: d = 0
    float t  = te[n];
    float T1 = interp1(t, Tt, Tv);
    float T2 = interp1(t + 10.f, Tt, Tv);
    float T3 = interp1(t + 20.f, Tt, Tv);
    float T4 = interp1(t + 30.f, Tt, Tv);
    a[0] = 3.75f * (T1 + 3.f * T2 + 3.f * T3 + T4);  // (h/8)*s0
    a[1] = 3.75f * (T1 + 2.f * T2 + T3);             // (h/8)*s1
    a[2] = 3.75f * (T1 * (1.f / 3.f) + T2);          // (h/8)*s2
    a[3] = 1.25f * T1;                               // (h/24)*s3
    a[4] = 1.f;                                      // g multiplier
}

// Zout[k] = M * Zin[k] + d_{k*SCH+i} ; optionally write to output row k*SCH+i+1
template <bool WRITE>
__global__ __launch_bounds__(256) void k_step(const float* __restrict__ Zin,
                                              float* __restrict__ Zout,
                                              const float* __restrict__ Mm,
                                              const float* __restrict__ vec,
                                              const float* __restrict__ alpha, int i,
                                              float* __restrict__ out) {
    __shared__ float Xs[32][33], Ms[32][33];
    int t = threadIdx.x;
    int r = t >> 3, c4 = (t & 7) * 4;
    int kb = blockIdx.y * 32, cb = blockIdx.x * 32;
    int krow = kb + r;
    float4 acc = {0.f, 0.f, 0.f, 0.f};
    for (int kt = 0; kt < 512; kt += 32) {
        float4 xv = {0.f, 0.f, 0.f, 0.f};
        if (krow < CCH) xv = *(const float4*)(Zin + (size_t)krow * 512 + kt + c4);
        Xs[r][c4] = xv.x; Xs[r][c4 + 1] = xv.y; Xs[r][c4 + 2] = xv.z; Xs[r][c4 + 3] = xv.w;
        float4 mv = *(const float4*)(Mm + (size_t)(cb + r) * 512 + kt + c4);  // NT: M row = out col
        Ms[r][c4] = mv.x; Ms[r][c4 + 1] = mv.y; Ms[r][c4 + 2] = mv.z; Ms[r][c4 + 3] = mv.w;
        __syncthreads();
        #pragma unroll
        for (int k = 0; k < 32; k++) {
            float x = Xs[r][k];
            acc.x += x * Ms[c4][k];     acc.y += x * Ms[c4 + 1][k];
            acc.z += x * Ms[c4 + 2][k]; acc.w += x * Ms[c4 + 3][k];
        }
        __syncthreads();
    }
    if (krow < CCH) {
        int n = krow * SCH + i;
        const float* a = alpha + (size_t)n * 8;
        float a0 = a[0], a1 = a[1], a2 = a[2], a3 = a[3], gm = a[4];
        int c = cb + c4;
        float4 res;
        res.x = acc.x + a0*vec[c]   + a1*vec[512+c]   + a2*vec[1024+c]   + a3*vec[1536+c]   + gm*vec[4096+c];
        res.y = acc.y + a0*vec[c+1] + a1*vec[512+c+1] + a2*vec[1024+c+1] + a3*vec[1536+c+1] + gm*vec[4096+c+1];
        res.z = acc.z + a0*vec[c+2] + a1*vec[512+c+2] + a2*vec[1024+c+2] + a3*vec[1536+c+2] + gm*vec[4096+c+2];
        res.w = acc.w + a0*vec[c+3] + a1*vec[512+c+3] + a2*vec[1024+c+3] + a3*vec[1536+c+3] + gm*vec[4096+c+3];
        *(float4*)(Zout + (size_t)krow * 512 + c) = res;
        if (WRITE) {
            int nout = n + 1;
            if (nout < TT) *(float4*)(out + (size_t)nout * 512 + c) = res;
        }
    }
}

// Aout[k] = Ain[k] + Q * Ain[k-shift]  (rows k < shift: copy)
__global__ __launch_bounds__(256) void k_scan(const float* __restrict__ Ain,
                                              float* __restrict__ Aout,
                                              const float* __restrict__ Qm, int shift) {
    __shared__ float Xs[32][33], Ms[32][33];
    int t = threadIdx.x;
    int r = t >> 3, c4 = (t & 7) * 4;
    int kb = blockIdx.y * 32, cb = blockIdx.x * 32;
    int krow = kb + r;
    int xrow = krow - shift;
    float4 acc = {0.f, 0.f, 0.f, 0.f};
    for (int kt = 0; kt < 512; kt += 32) {
        float4 xv = {0.f, 0.f, 0.f, 0.f};
        if (xrow >= 0 && krow < CCH + 1) xv = *(const float4*)(Ain + (size_t)xrow * 512 + kt + c4);
        Xs[r][c4] = xv.x; Xs[r][c4 + 1] = xv.y; Xs[r][c4 + 2] = xv.z; Xs[r][c4 + 3] = xv.w;
        float4 mv = *(const float4*)(Qm + (size_t)(cb + r) * 512 + kt + c4);
        Ms[r][c4] = mv.x; Ms[r][c4 + 1] = mv.y; Ms[r][c4 + 2] = mv.z; Ms[r][c4 + 3] = mv.w;
        __syncthreads();
        #pragma unroll
        for (int k = 0; k < 32; k++) {
            float x = Xs[r][k];
            acc.x += x * Ms[c4][k];     acc.y += x * Ms[c4 + 1][k];
            acc.z += x * Ms[c4 + 2][k]; acc.w += x * Ms[c4 + 3][k];
        }
        __syncthreads();
    }
    if (krow < CCH + 1) {
        int c = cb + c4;
        float4 av = *(const float4*)(Ain + (size_t)krow * 512 + c);
        float4 res = {av.x + acc.x, av.y + acc.y, av.z + acc.z, av.w + acc.w};
        *(float4*)(Aout + (size_t)krow * 512 + c) = res;
    }
}

__global__ void k_iv(const float* __restrict__ iv, float* __restrict__ out,
                     float* __restrict__ sa0) {
    int t = blockIdx.x * 256 + threadIdx.x;  // 512 threads
    out[t] = iv[t];
    sa0[t] = iv[t];
}

extern "C" void kernel_launch(void* const* d_in, const int* in_sizes, int n_in,
                              void* d_out, int out_size, void* d_ws, size_t ws_size,
                              hipStream_t stream) {
    const float* A  = (const float*)d_in[0];
    const float* B  = (const float*)d_in[1];
    const float* Q  = (const float*)d_in[2];
    const float* Tt = (const float*)d_in[3];
    const float* Tv = (const float*)d_in[4];
    const float* iv = (const float*)d_in[5];
    const float* te = (const float*)d_in[6];
    float* out = (float*)d_out;
    float* w = (float*)d_ws;

    float *Hm = w + OFF_H,  *Mm = w + OFF_M,  *T1 = w + OFF_T1, *T2 = w + OFF_T2;
    float *Q0 = w + OFF_Q0, *Q1 = w + OFF_Q1;
    float *vec = w + OFF_VEC, *al = w + OFF_ALPHA;
    float *Ya = w + OFF_YA, *Yb = w + OFF_YB, *SA = w + OFF_SA, *SB = w + OFF_SB;

    // --- setup: H, v/c, Krylov vectors, g, alphas ---
    k_scaleH<<<1024, 256, 0, stream>>>(A, Hm);
    k_prep_vc<<<1, 512, 0, stream>>>(B, Q, vec);
    k_matvec2<<<2, 256, 0, stream>>>(Hm, vec, vec + 2048, vec + 512, vec + 2560);        // w1,u1
    k_matvec2<<<2, 256, 0, stream>>>(Hm, vec + 512, vec + 2560, vec + 1024, vec + 3072); // w2,u2
    k_matvec2<<<2, 256, 0, stream>>>(Hm, vec + 1024, vec + 3072, vec + 1536, vec + 3584);// w3,u3
    k_gfin<<<1, 512, 0, stream>>>(vec);
    k_alphas<<<(NSTEP + 255) / 256, 256, 0, stream>>>(te, Tt, Tv, al);

    // --- M = I + H + H^2/2 + H^3/6 + H^4/24 ---
    dim3 g16(16, 16);
    k_mm_nn<<<g16, 256, 0, stream>>>(Hm, Hm, T1);   // H^2
    k_mm_nn<<<g16, 256, 0, stream>>>(T1, Hm, T2);   // H^3
    k_mm_nn<<<g16, 256, 0, stream>>>(T1, T1, Q0);   // H^4
    k_combineM<<<1024, 256, 0, stream>>>(Hm, T1, T2, Q0, Mm);

    // --- pass 1: zero-IC chunk-local scans; last step writes e_k into SA rows 1..CCH ---
    hipMemsetAsync(Ya, 0, (size_t)CCH * 512 * sizeof(float), stream);
    dim3 gstep(16, (CCH + 31) / 32);
    {
        const float* in = Ya;
        for (int i = 0; i < SCH; i++) {
            float* o = (i == SCH - 1) ? (SA + 512) : ((i & 1) ? Ya : Yb);
            k_step<false><<<gstep, 256, 0, stream>>>(in, o, Mm, vec, al, i, nullptr);
            in = o;
        }
    }
    k_iv<<<2, 256, 0, stream>>>(iv, out, SA);  // out row 0 and SA row 0 = iv

    // --- boundary scan: Hillis-Steele with Q_l = (M^16)^(2^l), truncated at 7 levels
    //     (||M^16|| < 0.3 -> M^16^128 ~ 1e-70, exactly 0 in f32) ---
    k_mm_nn<<<g16, 256, 0, stream>>>(Mm, Mm, Q0);  // M^2
    k_mm_nn<<<g16, 256, 0, stream>>>(Q0, Q0, Q1);  // M^4
    k_mm_nn<<<g16, 256, 0, stream>>>(Q1, Q1, Q0);  // M^8
    k_mm_nn<<<g16, 256, 0, stream>>>(Q0, Q0, Q1);  // M^16
    {
        float *qc = Q1, *qn = Q0;
        float *sin_ = SA, *sout = SB;
        dim3 gscan(16, (CCH + 1 + 31) / 32);
        for (int l = 0; l < 7; l++) {
            k_scan<<<gscan, 256, 0, stream>>>(sin_, sout, qc, 1 << l);
            float* tmp = sin_; sin_ = sout; sout = tmp;
            if (l < 6) {
                k_mm_nn<<<g16, 256, 0, stream>>>(qc, qc, qn);
                float* t2 = qc; qc = qn; qn = t2;
            }
        }
        // result (x at chunk starts) is in sin_ == SB after 7 levels
        // --- pass 2: true-IC recovery, writes output rows ---
        const float* zin = sin_;
        for (int i = 0; i < SCH; i++) {
            float* o = (i & 1) ? Ya : Yb;
            k_step<true><<<gstep, 256, 0, stream>>>(zin, o, Mm, vec, al, i, out);
            zin = o;
        }
    }
}

// Round 2
// 1352.548 us; speedup vs baseline: 1.3515x; 1.3515x over previous
//
#include <hip/hip_runtime.h>

#define TT    20000
#define SCH   8
#define CCH   2500        // TT / SCH
#define RROWS 2501
#define NDATA 2000
#define H_DT  30.0f
#define MSZ   262144      // 512*512

// workspace layout (floats)
static constexpr size_t OFF_H   = 0;                        // H = 30*A
static constexpr size_t OFF_H2  = OFF_H  + MSZ;             // H^2  (contiguous after H for batched B)
static constexpr size_t OFF_H3  = OFF_H2 + MSZ;             // H^3
static constexpr size_t OFF_H4  = OFF_H3 + MSZ;             // H^4
static constexpr size_t OFF_MP  = OFF_H4 + MSZ;             // M1T..M8T (8 matrices, (M^j)^T row-major)
static constexpr size_t OFF_SQ  = OFF_MP + 8*(size_t)MSZ;   // M16T,M32T,M64T,M128T
static constexpr size_t OFF_VEC = OFF_SQ + 4*(size_t)MSZ;   // B5T rows v,w1,w2,w3,g @0/512/1024/1536/2048; scratch c,u1,u2,u3 @2560/3072/3584/4096
static constexpr size_t OFF_GT  = OFF_VEC + 8192;           // 40x512: row-block j holds W_{7-j}^T
static constexpr size_t OFF_FJ  = OFF_GT + 20480;           // 8 x 40 x 512
static constexpr size_t OFF_AL  = OFF_FJ + 163840;          // 20000 x 5 alphas
static constexpr size_t OFF_SA  = OFF_AL + 102400;          // 2501 x 512
static constexpr size_t OFF_SB  = OFF_SA + 1310720;         // 2501 x 512

#define MICRO_FMA(a, b) do { \
  acc0.x += (a).x*(b).x; acc0.y += (a).x*(b).y; acc0.z += (a).x*(b).z; acc0.w += (a).x*(b).w; \
  acc1.x += (a).y*(b).x; acc1.y += (a).y*(b).y; acc1.z += (a).y*(b).z; acc1.w += (a).y*(b).w; \
  acc2.x += (a).z*(b).x; acc2.y += (a).z*(b).y; acc2.z += (a).z*(b).z; acc2.w += (a).z*(b).w; \
  acc3.x += (a).w*(b).x; acc3.y += (a).w*(b).y; acc3.z += (a).w*(b).z; acc3.w += (a).w*(b).w; \
} while (0)

// ---------------- setup kernels ----------------

__global__ void k_scaleH(const float* __restrict__ A, float* __restrict__ Hm) {
    int i = blockIdx.x * 256 + threadIdx.x;
    if (i < MSZ) Hm[i] = H_DT * A[i];
}

__global__ void k_prep_vc(const float* __restrict__ B, const float* __restrict__ Q,
                          float* __restrict__ vec) {
    int i = threadIdx.x;  // 512 threads
    float v = B[i * 9];
    float c = 0.f;
    #pragma unroll
    for (int j = 0; j < 8; j++) c += B[i * 9 + 1 + j] * Q[j];
    vec[i] = v;          // B5T row 0 = v
    vec[2560 + i] = c;   // scratch c
}

// y1 = H x1, y2 = H x2
__global__ void k_matvec2(const float* __restrict__ Hm, const float* __restrict__ x1,
                          const float* __restrict__ x2, float* __restrict__ y1,
                          float* __restrict__ y2) {
    __shared__ float s1[512], s2[512];
    int t = threadIdx.x;
    int r = blockIdx.x * 256 + t;
    s1[t] = x1[t]; s1[t + 256] = x1[t + 256];
    s2[t] = x2[t]; s2[t + 256] = x2[t + 256];
    __syncthreads();
    float a1 = 0.f, a2 = 0.f;
    const float* row = Hm + (size_t)r * 512;
    for (int k = 0; k < 512; k++) { float h = row[k]; a1 += h * s1[k]; a2 += h * s2[k]; }
    y1[r] = a1; y2[r] = a2;
}

__global__ void k_gfin(float* __restrict__ vec) {
    int i = threadIdx.x;  // 512
    vec[2048 + i] = H_DT * (vec[2560 + i] + 0.5f * vec[3072 + i] +
                            (1.f / 6.f) * vec[3584 + i] + (1.f / 24.f) * vec[4096 + i]);
}

__device__ __forceinline__ float interp1(float t, const float* __restrict__ xp,
                                         const float* __restrict__ fp) {
    if (t <= xp[0]) return fp[0];
    if (t >= xp[NDATA - 1]) return fp[NDATA - 1];
    int lo = 0, hi = NDATA - 1;
    while (hi - lo > 1) { int mid = (lo + hi) >> 1; if (xp[mid] <= t) lo = mid; else hi = mid; }
    float x0 = xp[lo], x1 = xp[lo + 1];
    return fp[lo] + (fp[lo + 1] - fp[lo]) * (t - x0) / (x1 - x0);
}

__global__ void k_alphas(const float* __restrict__ te, const float* __restrict__ Tt,
                         const float* __restrict__ Tv, float* __restrict__ alpha) {
    int n = blockIdx.x * 256 + threadIdx.x;
    if (n >= TT) return;
    float* a = alpha + (size_t)n * 5;
    if (n == TT - 1) { a[0] = a[1] = a[2] = a[3] = a[4] = 0.f; return; }  // padding step
    float t  = te[n];
    float T1 = interp1(t, Tt, Tv);
    float T2 = interp1(t + 10.f, Tt, Tv);
    float T3 = interp1(t + 20.f, Tt, Tv);
    float T4 = interp1(t + 30.f, Tt, Tv);
    a[0] = 3.75f * (T1 + 3.f * T2 + 3.f * T3 + T4);
    a[1] = 3.75f * (T1 + 2.f * T2 + T3);
    a[2] = 3.75f * (T1 * (1.f / 3.f) + T2);
    a[3] = 1.25f * T1;
    a[4] = 1.f;
}

// combine H-powers into M = I + H + H^2/2 + H^3/6 + H^4/24, stored TRANSPOSED into MP0
__global__ void k_combineMT(const float* __restrict__ Hm, const float* __restrict__ H2,
                            const float* __restrict__ H3, const float* __restrict__ H4,
                            float* __restrict__ MT) {
    __shared__ float Ms[32][33];
    int t = threadIdx.x;
    int rb = blockIdx.y * 32, cb = blockIdx.x * 32;
    int r = t >> 3, c4 = (t & 7) * 4;
    size_t base = (size_t)(rb + r) * 512 + cb + c4;
    #pragma unroll
    for (int j = 0; j < 4; j++) {
        float m = Hm[base + j] + 0.5f * H2[base + j] + (1.f / 6.f) * H3[base + j] +
                  (1.f / 24.f) * H4[base + j];
        if (rb + r == cb + c4 + j) m += 1.f;
        Ms[r][c4 + j] = m;
    }
    __syncthreads();
    int cc = t >> 3, rr4 = (t & 7) * 4;
    float4 o;
    o.x = Ms[rr4 + 0][cc]; o.y = Ms[rr4 + 1][cc]; o.z = Ms[rr4 + 2][cc]; o.w = Ms[rr4 + 3][cc];
    *(float4*)&MT[(size_t)(cb + cc) * 512 + rb + rr4] = o;
}

// ---------------- register-blocked GEMMs (64x64 tile, 4x4 micro) ----------------
// Z = A(512x512) @ B, B/Z are arrays of 512x512 row-major matrices selected by col-block.
__global__ __launch_bounds__(256) void k_pow_nn(const float* __restrict__ A,
                                                const float* __restrict__ B0,
                                                float* __restrict__ Z0) {
    __shared__ float As[16][68], Bs[16][68];
    int t = threadIdx.x;
    int tx = t & 15, ty = t >> 4;
    int ar = t & 63, ak = (t >> 6) * 4;
    int bk = t >> 4, bc = (t & 15) * 4;
    const float* Bm = B0 + (size_t)(blockIdx.x >> 3) * MSZ;
    float*       Zm = Z0 + (size_t)(blockIdx.x >> 3) * MSZ;
    int cb = (blockIdx.x & 7) * 64;
    int rb = blockIdx.y * 64;
    float4 acc0 = {0,0,0,0}, acc1 = {0,0,0,0}, acc2 = {0,0,0,0}, acc3 = {0,0,0,0};
    for (int kt = 0; kt < 512; kt += 16) {
        float4 av = *(const float4*)(A + (size_t)(rb + ar) * 512 + kt + ak);
        As[ak + 0][ar] = av.x; As[ak + 1][ar] = av.y; As[ak + 2][ar] = av.z; As[ak + 3][ar] = av.w;
        *(float4*)&Bs[bk][bc] = *(const float4*)(Bm + (size_t)(kt + bk) * 512 + cb + bc);
        __syncthreads();
        #pragma unroll
        for (int kk = 0; kk < 16; kk++) {
            float4 a = *(const float4*)&As[kk][ty * 4];
            float4 b = *(const float4*)&Bs[kk][tx * 4];
            MICRO_FMA(a, b);
        }
        __syncthreads();
    }
    size_t zb = (size_t)(rb + ty * 4) * 512 + cb + tx * 4;
    *(float4*)&Zm[zb]         = acc0;
    *(float4*)&Zm[zb + 512]   = acc1;
    *(float4*)&Zm[zb + 1024]  = acc2;
    *(float4*)&Zm[zb + 1536]  = acc3;
}

// Aout[k] = Ain[k] + Ain[k-shift] @ QT   (rows < shift: copy), R = RROWS rows
__global__ __launch_bounds__(256) void k_scan(const float* __restrict__ Ain,
                                              float* __restrict__ Aout,
                                              const float* __restrict__ QT, int shift) {
    __shared__ float As[16][68], Bs[16][68];
    int t = threadIdx.x;
    int tx = t & 15, ty = t >> 4;
    int ar = t & 63, ak = (t >> 6) * 4;
    int bk = t >> 4, bc = (t & 15) * 4;
    int cb = blockIdx.x * 64;
    int kb = blockIdx.y * 64;
    int xr = kb + ar - shift;
    bool aval = (xr >= 0) && (kb + ar < RROWS);
    float4 acc0 = {0,0,0,0}, acc1 = {0,0,0,0}, acc2 = {0,0,0,0}, acc3 = {0,0,0,0};
    for (int kt = 0; kt < 512; kt += 16) {
        float4 av = {0,0,0,0};
        if (aval) av = *(const float4*)(Ain + (size_t)xr * 512 + kt + ak);
        As[ak + 0][ar] = av.x; As[ak + 1][ar] = av.y; As[ak + 2][ar] = av.z; As[ak + 3][ar] = av.w;
        *(float4*)&Bs[bk][bc] = *(const float4*)(QT + (size_t)(kt + bk) * 512 + cb + bc);
        __syncthreads();
        #pragma unroll
        for (int kk = 0; kk < 16; kk++) {
            float4 a = *(const float4*)&As[kk][ty * 4];
            float4 b = *(const float4*)&Bs[kk][tx * 4];
            MICRO_FMA(a, b);
        }
        __syncthreads();
    }
    int col = cb + tx * 4;
    #pragma unroll
    for (int i = 0; i < 4; i++) {
        int krow = kb + ty * 4 + i;
        if (krow < RROWS) {
            float4 own = *(const float4*)(Ain + (size_t)krow * 512 + col);
            float4 a = (i == 0) ? acc0 : (i == 1) ? acc1 : (i == 2) ? acc2 : acc3;
            float4 res = {own.x + a.x, own.y + a.y, own.z + a.z, own.w + a.w};
            *(float4*)(Aout + (size_t)krow * 512 + col) = res;
        }
    }
}

// out[8k+j+1] = SS[k] @ M^{j+1}T + alphahat_k @ FJ_j     (j = blockIdx.x>>3)
__global__ __launch_bounds__(256) void k_final(const float* __restrict__ SS,
                                               const float* __restrict__ MP,
                                               const float* __restrict__ AL,
                                               const float* __restrict__ FJ,
                                               float* __restrict__ out) {
    __shared__ float As[16][68], Bs[16][68];
    __shared__ float Ah[64][41], Fs[40][68];
    int t = threadIdx.x;
    int tx = t & 15, ty = t >> 4;
    int ar = t & 63, ak = (t >> 6) * 4;
    int bk = t >> 4, bc = (t & 15) * 4;
    int j = blockIdx.x >> 3;
    const float* Bm = MP + (size_t)j * MSZ;
    int cb = (blockIdx.x & 7) * 64;
    int kb = blockIdx.y * 64;
    bool aval = (kb + ar < CCH);
    float4 acc0 = {0,0,0,0}, acc1 = {0,0,0,0}, acc2 = {0,0,0,0}, acc3 = {0,0,0,0};
    for (int kt = 0; kt < 512; kt += 16) {
        float4 av = {0,0,0,0};
        if (aval) av = *(const float4*)(SS + (size_t)(kb + ar) * 512 + kt + ak);
        As[ak + 0][ar] = av.x; As[ak + 1][ar] = av.y; As[ak + 2][ar] = av.z; As[ak + 3][ar] = av.w;
        *(float4*)&Bs[bk][bc] = *(const float4*)(Bm + (size_t)(kt + bk) * 512 + cb + bc);
        __syncthreads();
        #pragma unroll
        for (int kk = 0; kk < 16; kk++) {
            float4 a = *(const float4*)&As[kk][ty * 4];
            float4 b = *(const float4*)&Bs[kk][tx * 4];
            MICRO_FMA(a, b);
        }
        __syncthreads();
    }
    // stage alphahat rows (64x40) and FJ_j slice (40x64)
    #pragma unroll
    for (int m = 0; m < 10; m++) {
        int e = t + 256 * m;
        int row = e / 40, q = e - 40 * row;
        float v = 0.f;
        if (kb + row < CCH) v = AL[(size_t)(kb + row) * 40 + q];
        Ah[row][q] = v;
        int fq = e >> 6, fc = e & 63;
        Fs[fq][fc] = FJ[(size_t)j * 40 * 512 + (size_t)fq * 512 + cb + fc];
    }
    __syncthreads();
    #pragma unroll 8
    for (int q = 0; q < 40; q++) {
        float4 b = *(const float4*)&Fs[q][tx * 4];
        float a0 = Ah[ty * 4 + 0][q], a1 = Ah[ty * 4 + 1][q];
        float a2 = Ah[ty * 4 + 2][q], a3 = Ah[ty * 4 + 3][q];
        acc0.x += a0*b.x; acc0.y += a0*b.y; acc0.z += a0*b.z; acc0.w += a0*b.w;
        acc1.x += a1*b.x; acc1.y += a1*b.y; acc1.z += a1*b.z; acc1.w += a1*b.w;
        acc2.x += a2*b.x; acc2.y += a2*b.y; acc2.z += a2*b.z; acc2.w += a2*b.w;
        acc3.x += a3*b.x; acc3.y += a3*b.y; acc3.z += a3*b.z; acc3.w += a3*b.w;
    }
    int col = cb + tx * 4;
    #pragma unroll
    for (int i = 0; i < 4; i++) {
        int k = kb + ty * 4 + i;
        int n = 8 * k + j + 1;
        if (k < CCH && n < TT) {
            float4 a = (i == 0) ? acc0 : (i == 1) ? acc1 : (i == 2) ? acc2 : acc3;
            *(float4*)(out + (size_t)n * 512 + col) = a;
        }
    }
}

// E = AL(2500x40) @ GT(40x512) -> SA rows 1..2500
__global__ __launch_bounds__(256) void k_e40(const float* __restrict__ AL,
                                             const float* __restrict__ GT,
                                             float* __restrict__ SA1) {
    __shared__ float Ah[64][41], Bs[40][68];
    int t = threadIdx.x;
    int tx = t & 15, ty = t >> 4;
    int cb = blockIdx.x * 64;
    int kb = blockIdx.y * 64;
    #pragma unroll
    for (int m = 0; m < 10; m++) {
        int e = t + 256 * m;
        int row = e / 40, q = e - 40 * row;
        float v = 0.f;
        if (kb + row < CCH) v = AL[(size_t)(kb + row) * 40 + q];
        Ah[row][q] = v;
        int fq = e >> 6, fc = e & 63;
        Bs[fq][fc] = GT[(size_t)fq * 512 + cb + fc];
    }
    __syncthreads();
    float4 acc0 = {0,0,0,0}, acc1 = {0,0,0,0}, acc2 = {0,0,0,0}, acc3 = {0,0,0,0};
    #pragma unroll 8
    for (int q = 0; q < 40; q++) {
        float4 b = *(const float4*)&Bs[q][tx * 4];
        float a0 = Ah[ty * 4 + 0][q], a1 = Ah[ty * 4 + 1][q];
        float a2 = Ah[ty * 4 + 2][q], a3 = Ah[ty * 4 + 3][q];
        acc0.x += a0*b.x; acc0.y += a0*b.y; acc0.z += a0*b.z; acc0.w += a0*b.w;
        acc1.x += a1*b.x; acc1.y += a1*b.y; acc1.z += a1*b.z; acc1.w += a1*b.w;
        acc2.x += a2*b.x; acc2.y += a2*b.y; acc2.z += a2*b.z; acc2.w += a2*b.w;
        acc3.x += a3*b.x; acc3.y += a3*b.y; acc3.z += a3*b.z; acc3.w += a3*b.w;
    }
    int col = cb + tx * 4;
    #pragma unroll
    for (int i = 0; i < 4; i++) {
        int k = kb + ty * 4 + i;
        if (k < CCH) {
            float4 a = (i == 0) ? acc0 : (i == 1) ? acc1 : (i == 2) ? acc2 : acc3;
            *(float4*)(SA1 + (size_t)k * 512 + col) = a;
        }
    }
}

// small NN GEMM: Z(rows x 512) = A(rows x 512) @ B(512x512), rows <= 20
__global__ void k_small_nn(const float* __restrict__ A, const float* __restrict__ B,
                           float* __restrict__ Z, int rows) {
    int t = threadIdx.x;
    int col = blockIdx.x * 64 + (t & 63);
    int rg = t >> 6;
    float acc[5] = {0.f, 0.f, 0.f, 0.f, 0.f};
    for (int kk = 0; kk < 512; kk++) {
        float b = B[(size_t)kk * 512 + col];
        #pragma unroll
        for (int s = 0; s < 5; s++) {
            int r = rg + 4 * s;
            if (r < rows) acc[s] += A[(size_t)r * 512 + kk] * b;
        }
    }
    #pragma unroll
    for (int s = 0; s < 5; s++) {
        int r = rg + 4 * s;
        if (r < rows) Z[(size_t)r * 512 + col] = acc[s];
    }
}

__global__ void k_copyW0(const float* __restrict__ vec, float* __restrict__ GT) {
    int e = blockIdx.x * 256 + threadIdx.x;  // 2560
    if (e < 2560) GT[35 * 512 + e] = vec[e];
}

// FJ[j, i*5+q, c] = W_{j-i}T[q,c] = GT[(7-(j-i))*5+q, c] for i<=j else 0
__global__ void k_fj(const float* __restrict__ GT, float* __restrict__ FJ) {
    int idx = blockIdx.x * 256 + threadIdx.x;
    if (idx >= 8 * 40 * 512) return;
    int c = idx & 511;
    int jr = idx >> 9;
    int j = jr / 40, r = jr - 40 * j;
    int i = r / 5, q = r - 5 * i;
    float v = 0.f;
    if (i <= j) v = GT[((7 - (j - i)) * 5 + q) * 512 + c];
    FJ[idx] = v;
}

__global__ void k_iv(const float* __restrict__ iv, float* __restrict__ out,
                     float* __restrict__ sa0) {
    int t = blockIdx.x * 256 + threadIdx.x;  // 512
    out[t] = iv[t];
    sa0[t] = iv[t];
}

extern "C" void kernel_launch(void* const* d_in, const int* in_sizes, int n_in,
                              void* d_out, int out_size, void* d_ws, size_t ws_size,
                              hipStream_t stream) {
    const float* A  = (const float*)d_in[0];
    const float* B  = (const float*)d_in[1];
    const float* Q  = (const float*)d_in[2];
    const float* Tt = (const float*)d_in[3];
    const float* Tv = (const float*)d_in[4];
    const float* iv = (const float*)d_in[5];
    const float* te = (const float*)d_in[6];
    float* out = (float*)d_out;
    float* w = (float*)d_ws;

    float *Hm = w + OFF_H, *H2 = w + OFF_H2, *H3 = w + OFF_H3, *H4 = w + OFF_H4;
    float *MP = w + OFF_MP, *SQ = w + OFF_SQ;
    float *vec = w + OFF_VEC, *GT = w + OFF_GT, *FJ = w + OFF_FJ, *AL = w + OFF_AL;
    float *SA = w + OFF_SA, *SB = w + OFF_SB;

    // setup
    k_scaleH<<<1024, 256, 0, stream>>>(A, Hm);
    k_prep_vc<<<1, 512, 0, stream>>>(B, Q, vec);
    k_matvec2<<<2, 256, 0, stream>>>(Hm, vec, vec + 2560, vec + 512, vec + 3072);
    k_matvec2<<<2, 256, 0, stream>>>(Hm, vec + 512, vec + 3072, vec + 1024, vec + 3584);
    k_matvec2<<<2, 256, 0, stream>>>(Hm, vec + 1024, vec + 3584, vec + 1536, vec + 4096);
    k_gfin<<<1, 512, 0, stream>>>(vec);
    k_alphas<<<(TT + 255) / 256, 256, 0, stream>>>(te, Tt, Tv, AL);

    // H powers and M (transposed)
    k_pow_nn<<<dim3(8, 8), 256, 0, stream>>>(Hm, Hm, H2);          // H^2
    k_pow_nn<<<dim3(16, 8), 256, 0, stream>>>(H2, Hm, H3);         // [H^3 | H^4] (B = [H|H2])
    k_combineMT<<<dim3(16, 16), 256, 0, stream>>>(Hm, H2, H3, H4, MP);  // M1T

    // M powers (all transposed): M2T, [M3,M4]T, [M5..M8]T
    k_pow_nn<<<dim3(8, 8), 256, 0, stream>>>(MP, MP, MP + MSZ);
    k_pow_nn<<<dim3(16, 8), 256, 0, stream>>>(MP + MSZ, MP, MP + 2 * (size_t)MSZ);
    k_pow_nn<<<dim3(32, 8), 256, 0, stream>>>(MP + 3 * (size_t)MSZ, MP, MP + 4 * (size_t)MSZ);
    // scan squarings: M16T, M32T, M64T, M128T
    k_pow_nn<<<dim3(8, 8), 256, 0, stream>>>(MP + 7 * (size_t)MSZ, MP + 7 * (size_t)MSZ, SQ);
    k_pow_nn<<<dim3(8, 8), 256, 0, stream>>>(SQ, SQ, SQ + MSZ);
    k_pow_nn<<<dim3(8, 8), 256, 0, stream>>>(SQ + MSZ, SQ + MSZ, SQ + 2 * (size_t)MSZ);
    k_pow_nn<<<dim3(8, 8), 256, 0, stream>>>(SQ + 2 * (size_t)MSZ, SQ + 2 * (size_t)MSZ, SQ + 3 * (size_t)MSZ);

    // GT chain: W0T copy, W1T, [W3,W2]T, [W7..W4]T
    k_copyW0<<<10, 256, 0, stream>>>(vec, GT);
    k_small_nn<<<8, 256, 0, stream>>>(GT + 35 * 512, MP, GT + 30 * 512, 5);
    k_small_nn<<<8, 256, 0, stream>>>(GT + 30 * 512, MP + MSZ, GT + 20 * 512, 10);
    k_small_nn<<<8, 256, 0, stream>>>(GT + 20 * 512, MP + 3 * (size_t)MSZ, GT, 20);
    k_fj<<<640, 256, 0, stream>>>(GT, FJ);

    // E = AL @ GT -> SA rows 1..2500 ; SA row0 = iv ; out row0 = iv
    k_e40<<<dim3(8, 40), 256, 0, stream>>>(AL, GT, SA + 512);
    k_iv<<<2, 256, 0, stream>>>(iv, out, SA);

    // 5-level Hillis-Steele boundary scan (bases M8T, M16T, M32T, M64T, M128T)
    dim3 gscan(8, 40);
    k_scan<<<gscan, 256, 0, stream>>>(SA, SB, MP + 7 * (size_t)MSZ, 1);
    k_scan<<<gscan, 256, 0, stream>>>(SB, SA, SQ, 2);
    k_scan<<<gscan, 256, 0, stream>>>(SA, SB, SQ + MSZ, 4);
    k_scan<<<gscan, 256, 0, stream>>>(SB, SA, SQ + 2 * (size_t)MSZ, 8);
    k_scan<<<gscan, 256, 0, stream>>>(SA, SB, SQ + 3 * (size_t)MSZ, 16);

    // final: out[8k+j+1] = SS[k] @ M^{j+1}T + alphahat_k @ FJ_j
    k_final<<<dim3(64, 40), 256, 0, stream>>>(SB, MP, AL, FJ, out);
}

// Round 4
// 756.868 us; speedup vs baseline: 2.4151x; 1.7870x over previous
//
#include <hip/hip_runtime.h>

#define TT    20000
#define SCH   8
#define CCH   2500        // TT / SCH
#define RROWS 2501
#define NDATA 2000
#define H_DT  30.0f
#define MSZ   262144      // 512*512

// workspace layout (floats)
static constexpr size_t OFF_H   = 0;                        // H = 30*A
static constexpr size_t OFF_H2  = OFF_H  + MSZ;             // H^2
static constexpr size_t OFF_H3  = OFF_H2 + MSZ;             // H^3
static constexpr size_t OFF_H4  = OFF_H3 + MSZ;             // H^4
static constexpr size_t OFF_MP  = OFF_H4 + MSZ;             // M1T..M8T
static constexpr size_t OFF_SQ  = OFF_MP + 8*(size_t)MSZ;   // M16T,M32T,M64T,M128T
static constexpr size_t OFF_VEC = OFF_SQ + 4*(size_t)MSZ;   // v,w1,w2,w3,g @0/512/1024/1536/2048; scratch c,u1,u2,u3 @2560..
static constexpr size_t OFF_GT  = OFF_VEC + 8192;           // 40x512: row-block b holds W_{7-b}^T
static constexpr size_t OFF_FJ  = OFF_GT + 20480;           // 8 x 40 x 512
static constexpr size_t OFF_AL  = OFF_FJ + 163840;          // 20000 x 5 alphas
static constexpr size_t OFF_SA  = OFF_AL + 102400;          // 2501 x 512
static constexpr size_t OFF_SB  = OFF_SA + 1310720;         // 2501 x 512

#define MICRO_FMA(a, b) do { \
  acc0.x += (a).x*(b).x; acc0.y += (a).x*(b).y; acc0.z += (a).x*(b).z; acc0.w += (a).x*(b).w; \
  acc1.x += (a).y*(b).x; acc1.y += (a).y*(b).y; acc1.z += (a).y*(b).z; acc1.w += (a).y*(b).w; \
  acc2.x += (a).z*(b).x; acc2.y += (a).z*(b).y; acc2.z += (a).z*(b).z; acc2.w += (a).z*(b).w; \
  acc3.x += (a).w*(b).x; acc3.y += (a).w*(b).y; acc3.z += (a).w*(b).z; acc3.w += (a).w*(b).w; \
} while (0)

// ---------------- setup kernels ----------------

__global__ void k_scaleH(const float* __restrict__ A, float* __restrict__ Hm) {
    int i = blockIdx.x * 256 + threadIdx.x;
    if (i < MSZ) Hm[i] = H_DT * A[i];
}

__global__ void k_prep_vc(const float* __restrict__ B, const float* __restrict__ Q,
                          float* __restrict__ vec) {
    int i = threadIdx.x;  // 512 threads
    float v = B[i * 9];
    float c = 0.f;
    #pragma unroll
    for (int j = 0; j < 8; j++) c += B[i * 9 + 1 + j] * Q[j];
    vec[i] = v;          // row 0 = v
    vec[2560 + i] = c;   // scratch c
}

// y1 = H x1, y2 = H x2
__global__ void k_matvec2(const float* __restrict__ Hm, const float* __restrict__ x1,
                          const float* __restrict__ x2, float* __restrict__ y1,
                          float* __restrict__ y2) {
    __shared__ float s1[512], s2[512];
    int t = threadIdx.x;
    int r = blockIdx.x * 256 + t;
    s1[t] = x1[t]; s1[t + 256] = x1[t + 256];
    s2[t] = x2[t]; s2[t + 256] = x2[t + 256];
    __syncthreads();
    float a1 = 0.f, a2 = 0.f;
    const float* row = Hm + (size_t)r * 512;
    for (int k = 0; k < 512; k++) { float h = row[k]; a1 += h * s1[k]; a2 += h * s2[k]; }
    y1[r] = a1; y2[r] = a2;
}

__global__ void k_gfin(float* __restrict__ vec) {
    int i = threadIdx.x;  // 512
    vec[2048 + i] = H_DT * (vec[2560 + i] + 0.5f * vec[3072 + i] +
                            (1.f / 6.f) * vec[3584 + i] + (1.f / 24.f) * vec[4096 + i]);
}

__device__ __forceinline__ float interp1(float t, const float* __restrict__ xp,
                                         const float* __restrict__ fp) {
    if (t <= xp[0]) return fp[0];
    if (t >= xp[NDATA - 1]) return fp[NDATA - 1];
    int lo = 0, hi = NDATA - 1;
    while (hi - lo > 1) { int mid = (lo + hi) >> 1; if (xp[mid] <= t) lo = mid; else hi = mid; }
    float x0 = xp[lo], x1 = xp[lo + 1];
    return fp[lo] + (fp[lo + 1] - fp[lo]) * (t - x0) / (x1 - x0);
}

__global__ void k_alphas(const float* __restrict__ te, const float* __restrict__ Tt,
                         const float* __restrict__ Tv, float* __restrict__ alpha) {
    int n = blockIdx.x * 256 + threadIdx.x;
    if (n >= TT) return;
    float* a = alpha + (size_t)n * 5;
    if (n == TT - 1) { a[0] = a[1] = a[2] = a[3] = a[4] = 0.f; return; }  // padding step
    float t  = te[n];
    float T1 = interp1(t, Tt, Tv);
    float T2 = interp1(t + 10.f, Tt, Tv);
    float T3 = interp1(t + 20.f, Tt, Tv);
    float T4 = interp1(t + 30.f, Tt, Tv);
    a[0] = 3.75f * (T1 + 3.f * T2 + 3.f * T3 + T4);
    a[1] = 3.75f * (T1 + 2.f * T2 + T3);
    a[2] = 3.75f * (T1 * (1.f / 3.f) + T2);
    a[3] = 1.25f * T1;
    a[4] = 1.f;
}

// combine H-powers into M = I + H + H^2/2 + H^3/6 + H^4/24, stored TRANSPOSED into MP0
__global__ void k_combineMT(const float* __restrict__ Hm, const float* __restrict__ H2,
                            const float* __restrict__ H3, const float* __restrict__ H4,
                            float* __restrict__ MT) {
    __shared__ float Ms[32][33];
    int t = threadIdx.x;
    int rb = blockIdx.y * 32, cb = blockIdx.x * 32;
    int r = t >> 3, c4 = (t & 7) * 4;
    size_t base = (size_t)(rb + r) * 512 + cb + c4;
    #pragma unroll
    for (int j = 0; j < 4; j++) {
        float m = Hm[base + j] + 0.5f * H2[base + j] + (1.f / 6.f) * H3[base + j] +
                  (1.f / 24.f) * H4[base + j];
        if (rb + r == cb + c4 + j) m += 1.f;
        Ms[r][c4 + j] = m;
    }
    __syncthreads();
    int cc = t >> 3, rr4 = (t & 7) * 4;
    float4 o;
    o.x = Ms[rr4 + 0][cc]; o.y = Ms[rr4 + 1][cc]; o.z = Ms[rr4 + 2][cc]; o.w = Ms[rr4 + 3][cc];
    *(float4*)&MT[(size_t)(cb + cc) * 512 + rb + rr4] = o;
}

// ---------------- register-blocked GEMMs (64x64 tile, 4x4 micro) ----------------
// Z = A(512x512) @ B, B/Z selected by blockIdx.x>>3.
__global__ __launch_bounds__(256) void k_pow_nn(const float* __restrict__ A,
                                                const float* __restrict__ B0,
                                                float* __restrict__ Z0) {
    __shared__ float As[16][68], Bs[16][68];
    int t = threadIdx.x;
    int tx = t & 15, ty = t >> 4;
    int ar = t & 63, ak = (t >> 6) * 4;
    int bk = t >> 4, bc = (t & 15) * 4;
    const float* Bm = B0 + (size_t)(blockIdx.x >> 3) * MSZ;
    float*       Zm = Z0 + (size_t)(blockIdx.x >> 3) * MSZ;
    int cb = (blockIdx.x & 7) * 64;
    int rb = blockIdx.y * 64;
    float4 acc0 = {0,0,0,0}, acc1 = {0,0,0,0}, acc2 = {0,0,0,0}, acc3 = {0,0,0,0};
    for (int kt = 0; kt < 512; kt += 16) {
        float4 av = *(const float4*)(A + (size_t)(rb + ar) * 512 + kt + ak);
        As[ak + 0][ar] = av.x; As[ak + 1][ar] = av.y; As[ak + 2][ar] = av.z; As[ak + 3][ar] = av.w;
        *(float4*)&Bs[bk][bc] = *(const float4*)(Bm + (size_t)(kt + bk) * 512 + cb + bc);
        __syncthreads();
        #pragma unroll
        for (int kk = 0; kk < 16; kk++) {
            float4 a = *(const float4*)&As[kk][ty * 4];
            float4 b = *(const float4*)&Bs[kk][tx * 4];
            MICRO_FMA(a, b);
        }
        __syncthreads();
    }
    size_t zb = (size_t)(rb + ty * 4) * 512 + cb + tx * 4;
    *(float4*)&Zm[zb]         = acc0;
    *(float4*)&Zm[zb + 512]   = acc1;
    *(float4*)&Zm[zb + 1024]  = acc2;
    *(float4*)&Zm[zb + 1536]  = acc3;
}

// Aout[k] = Ain[k] + Ain[k-shift] @ QT   (rows < shift: copy)
__global__ __launch_bounds__(256) void k_scan(const float* __restrict__ Ain,
                                              float* __restrict__ Aout,
                                              const float* __restrict__ QT, int shift) {
    __shared__ float As[16][68], Bs[16][68];
    int t = threadIdx.x;
    int tx = t & 15, ty = t >> 4;
    int ar = t & 63, ak = (t >> 6) * 4;
    int bk = t >> 4, bc = (t & 15) * 4;
    int cb = blockIdx.x * 64;
    int kb = blockIdx.y * 64;
    int xr = kb + ar - shift;
    bool aval = (xr >= 0) && (kb + ar < RROWS);
    float4 acc0 = {0,0,0,0}, acc1 = {0,0,0,0}, acc2 = {0,0,0,0}, acc3 = {0,0,0,0};
    for (int kt = 0; kt < 512; kt += 16) {
        float4 av = {0,0,0,0};
        if (aval) av = *(const float4*)(Ain + (size_t)xr * 512 + kt + ak);
        As[ak + 0][ar] = av.x; As[ak + 1][ar] = av.y; As[ak + 2][ar] = av.z; As[ak + 3][ar] = av.w;
        *(float4*)&Bs[bk][bc] = *(const float4*)(QT + (size_t)(kt + bk) * 512 + cb + bc);
        __syncthreads();
        #pragma unroll
        for (int kk = 0; kk < 16; kk++) {
            float4 a = *(const float4*)&As[kk][ty * 4];
            float4 b = *(const float4*)&Bs[kk][tx * 4];
            MICRO_FMA(a, b);
        }
        __syncthreads();
    }
    int col = cb + tx * 4;
    #pragma unroll
    for (int i = 0; i < 4; i++) {
        int krow = kb + ty * 4 + i;
        if (krow < RROWS) {
            float4 own = *(const float4*)(Ain + (size_t)krow * 512 + col);
            float4 a = (i == 0) ? acc0 : (i == 1) ? acc1 : (i == 2) ? acc2 : acc3;
            float4 res = {own.x + a.x, own.y + a.y, own.z + a.z, own.w + a.w};
            *(float4*)(Aout + (size_t)krow * 512 + col) = res;
        }
    }
}

// out[8k+j+1] = SS[k] @ M^{j+1}T + alphahat_k @ FJ_j     (j = blockIdx.x>>3)
__global__ __launch_bounds__(256) void k_final(const float* __restrict__ SS,
                                               const float* __restrict__ MP,
                                               const float* __restrict__ AL,
                                               const float* __restrict__ FJ,
                                               float* __restrict__ out) {
    __shared__ float As[16][68], Bs[16][68];
    __shared__ float Ah[64][41], Fs[40][68];
    int t = threadIdx.x;
    int tx = t & 15, ty = t >> 4;
    int ar = t & 63, ak = (t >> 6) * 4;
    int bk = t >> 4, bc = (t & 15) * 4;
    int j = blockIdx.x >> 3;
    const float* Bm = MP + (size_t)j * MSZ;
    int cb = (blockIdx.x & 7) * 64;
    int kb = blockIdx.y * 64;
    bool aval = (kb + ar < CCH);
    float4 acc0 = {0,0,0,0}, acc1 = {0,0,0,0}, acc2 = {0,0,0,0}, acc3 = {0,0,0,0};
    for (int kt = 0; kt < 512; kt += 16) {
        float4 av = {0,0,0,0};
        if (aval) av = *(const float4*)(SS + (size_t)(kb + ar) * 512 + kt + ak);
        As[ak + 0][ar] = av.x; As[ak + 1][ar] = av.y; As[ak + 2][ar] = av.z; As[ak + 3][ar] = av.w;
        *(float4*)&Bs[bk][bc] = *(const float4*)(Bm + (size_t)(kt + bk) * 512 + cb + bc);
        __syncthreads();
        #pragma unroll
        for (int kk = 0; kk < 16; kk++) {
            float4 a = *(const float4*)&As[kk][ty * 4];
            float4 b = *(const float4*)&Bs[kk][tx * 4];
            MICRO_FMA(a, b);
        }
        __syncthreads();
    }
    // rank-40 forcing epilogue
    #pragma unroll
    for (int m = 0; m < 10; m++) {
        int e = t + 256 * m;
        int row = e / 40, q = e - 40 * row;
        float v = 0.f;
        if (kb + row < CCH) v = AL[(size_t)(kb + row) * 40 + q];
        Ah[row][q] = v;
        int fq = e >> 6, fc = e & 63;
        Fs[fq][fc] = FJ[(size_t)j * 40 * 512 + (size_t)fq * 512 + cb + fc];
    }
    __syncthreads();
    #pragma unroll 8
    for (int q = 0; q < 40; q++) {
        float4 b = *(const float4*)&Fs[q][tx * 4];
        float a0 = Ah[ty * 4 + 0][q], a1 = Ah[ty * 4 + 1][q];
        float a2 = Ah[ty * 4 + 2][q], a3 = Ah[ty * 4 + 3][q];
        acc0.x += a0*b.x; acc0.y += a0*b.y; acc0.z += a0*b.z; acc0.w += a0*b.w;
        acc1.x += a1*b.x; acc1.y += a1*b.y; acc1.z += a1*b.z; acc1.w += a1*b.w;
        acc2.x += a2*b.x; acc2.y += a2*b.y; acc2.z += a2*b.z; acc2.w += a2*b.w;
        acc3.x += a3*b.x; acc3.y += a3*b.y; acc3.z += a3*b.z; acc3.w += a3*b.w;
    }
    int col = cb + tx * 4;
    #pragma unroll
    for (int i = 0; i < 4; i++) {
        int k = kb + ty * 4 + i;
        int n = 8 * k + j + 1;
        if (k < CCH && n < TT) {
            float4 a = (i == 0) ? acc0 : (i == 1) ? acc1 : (i == 2) ? acc2 : acc3;
            *(float4*)(out + (size_t)n * 512 + col) = a;
        }
    }
}

// E = AL(2500x40) @ GT(40x512) -> SA rows 1..2500
__global__ __launch_bounds__(256) void k_e40(const float* __restrict__ AL,
                                             const float* __restrict__ GT,
                                             float* __restrict__ SA1) {
    __shared__ float Ah[64][41], Bs[40][68];
    int t = threadIdx.x;
    int tx = t & 15, ty = t >> 4;
    int cb = blockIdx.x * 64;
    int kb = blockIdx.y * 64;
    #pragma unroll
    for (int m = 0; m < 10; m++) {
        int e = t + 256 * m;
        int row = e / 40, q = e - 40 * row;
        float v = 0.f;
        if (kb + row < CCH) v = AL[(size_t)(kb + row) * 40 + q];
        Ah[row][q] = v;
        int fq = e >> 6, fc = e & 63;
        Bs[fq][fc] = GT[(size_t)fq * 512 + cb + fc];
    }
    __syncthreads();
    float4 acc0 = {0,0,0,0}, acc1 = {0,0,0,0}, acc2 = {0,0,0,0}, acc3 = {0,0,0,0};
    #pragma unroll 8
    for (int q = 0; q < 40; q++) {
        float4 b = *(const float4*)&Bs[q][tx * 4];
        float a0 = Ah[ty * 4 + 0][q], a1 = Ah[ty * 4 + 1][q];
        float a2 = Ah[ty * 4 + 2][q], a3 = Ah[ty * 4 + 3][q];
        acc0.x += a0*b.x; acc0.y += a0*b.y; acc0.z += a0*b.z; acc0.w += a0*b.w;
        acc1.x += a1*b.x; acc1.y += a1*b.y; acc1.z += a1*b.z; acc1.w += a1*b.w;
        acc2.x += a2*b.x; acc2.y += a2*b.y; acc2.z += a2*b.z; acc2.w += a2*b.w;
        acc3.x += a3*b.x; acc3.y += a3*b.y; acc3.z += a3*b.z; acc3.w += a3*b.w;
    }
    int col = cb + tx * 4;
    #pragma unroll
    for (int i = 0; i < 4; i++) {
        int k = kb + ty * 4 + i;
        if (k < CCH) {
            float4 a = (i == 0) ? acc0 : (i == 1) ? acc1 : (i == 2) ? acc2 : acc3;
            *(float4*)(SA1 + (size_t)k * 512 + col) = a;
        }
    }
}

// W_jT (5x512) = W0T @ (M^j)T for j=1..7, fully parallel.
// grid: (8 col-blocks, 7 j). Block: 256 threads, wave w handles K-quarter w.
__global__ __launch_bounds__(256) void k_wgen(const float* __restrict__ vec,
                                              const float* __restrict__ MP,
                                              float* __restrict__ GT) {
    __shared__ float Ws[5][512];
    __shared__ float red[4][5][64];
    int t = threadIdx.x;
    int j = blockIdx.y + 1;                      // 1..7
    const float* Mj = MP + (size_t)(j - 1) * MSZ;
    int cb = blockIdx.x * 64;
    for (int e = t; e < 2560; e += 256) Ws[e >> 9][e & 511] = vec[e];
    __syncthreads();
    int col = t & 63;
    int kq = t >> 6;                             // wave id = K-quarter
    float acc[5] = {0.f, 0.f, 0.f, 0.f, 0.f};
    int k0 = kq * 128;
    #pragma unroll 4
    for (int k = k0; k < k0 + 128; k++) {
        float m = Mj[(size_t)k * 512 + cb + col];
        acc[0] += Ws[0][k] * m;
        acc[1] += Ws[1][k] * m;
        acc[2] += Ws[2][k] * m;
        acc[3] += Ws[3][k] * m;
        acc[4] += Ws[4][k] * m;
    }
    #pragma unroll
    for (int r = 0; r < 5; r++) red[kq][r][col] = acc[r];
    __syncthreads();
    // 320 outputs (5 rows x 64 cols) from 256 threads: strided loop.
    // (round-3 bug: `if (t < 320)` never produced r==4 with a 256-thread block)
    for (int idx = t; idx < 320; idx += 256) {
        int r = idx >> 6, c = idx & 63;
        float s = red[0][r][c] + red[1][r][c] + red[2][r][c] + red[3][r][c];
        GT[((size_t)(7 - j) * 5 + r) * 512 + cb + c] = s;
    }
}

__global__ void k_copyW0(const float* __restrict__ vec, float* __restrict__ GT) {
    int e = blockIdx.x * 256 + threadIdx.x;  // 2560
    if (e < 2560) GT[35 * 512 + e] = vec[e];
}

// FJ[j, i*5+q, c] = W_{j-i}T[q,c] = GT[(7-(j-i))*5+q, c] for i<=j else 0
__global__ void k_fj(const float* __restrict__ GT, float* __restrict__ FJ) {
    int idx = blockIdx.x * 256 + threadIdx.x;
    if (idx >= 8 * 40 * 512) return;
    int c = idx & 511;
    int jr = idx >> 9;
    int j = jr / 40, r = jr - 40 * j;
    int i = r / 5, q = r - 5 * i;
    float v = 0.f;
    if (i <= j) v = GT[((7 - (j - i)) * 5 + q) * 512 + c];
    FJ[idx] = v;
}

__global__ void k_iv(const float* __restrict__ iv, float* __restrict__ out,
                     float* __restrict__ sa0) {
    int t = blockIdx.x * 256 + threadIdx.x;  // 512
    out[t] = iv[t];
    sa0[t] = iv[t];
}

extern "C" void kernel_launch(void* const* d_in, const int* in_sizes, int n_in,
                              void* d_out, int out_size, void* d_ws, size_t ws_size,
                              hipStream_t stream) {
    const float* A  = (const float*)d_in[0];
    const float* B  = (const float*)d_in[1];
    const float* Q  = (const float*)d_in[2];
    const float* Tt = (const float*)d_in[3];
    const float* Tv = (const float*)d_in[4];
    const float* iv = (const float*)d_in[5];
    const float* te = (const float*)d_in[6];
    float* out = (float*)d_out;
    float* w = (float*)d_ws;

    float *Hm = w + OFF_H, *H2 = w + OFF_H2, *H3 = w + OFF_H3, *H4 = w + OFF_H4;
    float *MP = w + OFF_MP, *SQ = w + OFF_SQ;
    float *vec = w + OFF_VEC, *GT = w + OFF_GT, *FJ = w + OFF_FJ, *AL = w + OFF_AL;
    float *SA = w + OFF_SA, *SB = w + OFF_SB;

    // setup
    k_scaleH<<<1024, 256, 0, stream>>>(A, Hm);
    k_prep_vc<<<1, 512, 0, stream>>>(B, Q, vec);
    k_matvec2<<<2, 256, 0, stream>>>(Hm, vec, vec + 2560, vec + 512, vec + 3072);
    k_matvec2<<<2, 256, 0, stream>>>(Hm, vec + 512, vec + 3072, vec + 1024, vec + 3584);
    k_matvec2<<<2, 256, 0, stream>>>(Hm, vec + 1024, vec + 3584, vec + 1536, vec + 4096);
    k_gfin<<<1, 512, 0, stream>>>(vec);
    k_alphas<<<(TT + 255) / 256, 256, 0, stream>>>(te, Tt, Tv, AL);

    // H powers and M (transposed)
    k_pow_nn<<<dim3(8, 8), 256, 0, stream>>>(Hm, Hm, H2);          // H^2
    k_pow_nn<<<dim3(16, 8), 256, 0, stream>>>(H2, Hm, H3);         // [H^3 | H^4]
    k_combineMT<<<dim3(16, 16), 256, 0, stream>>>(Hm, H2, H3, H4, MP);  // M1T

    // M powers (transposed): M2T, [M3,M4]T, [M5..M8]T
    k_pow_nn<<<dim3(8, 8), 256, 0, stream>>>(MP, MP, MP + MSZ);
    k_pow_nn<<<dim3(16, 8), 256, 0, stream>>>(MP + MSZ, MP, MP + 2 * (size_t)MSZ);
    k_pow_nn<<<dim3(32, 8), 256, 0, stream>>>(MP + 3 * (size_t)MSZ, MP, MP + 4 * (size_t)MSZ);

    // W matrices: all 7 in one parallel launch (uses M1T..M7T), then FJ
    k_copyW0<<<10, 256, 0, stream>>>(vec, GT);
    k_wgen<<<dim3(8, 7), 256, 0, stream>>>(vec, MP, GT);
    k_fj<<<640, 256, 0, stream>>>(GT, FJ);

    // scan squarings: M16T, M32T, M64T, M128T
    k_pow_nn<<<dim3(8, 8), 256, 0, stream>>>(MP + 7 * (size_t)MSZ, MP + 7 * (size_t)MSZ, SQ);
    k_pow_nn<<<dim3(8, 8), 256, 0, stream>>>(SQ, SQ, SQ + MSZ);
    k_pow_nn<<<dim3(8, 8), 256, 0, stream>>>(SQ + MSZ, SQ + MSZ, SQ + 2 * (size_t)MSZ);
    k_pow_nn<<<dim3(8, 8), 256, 0, stream>>>(SQ + 2 * (size_t)MSZ, SQ + 2 * (size_t)MSZ, SQ + 3 * (size_t)MSZ);

    // E = AL @ GT -> SA rows 1..2500 ; SA row0 = iv ; out row0 = iv
    k_e40<<<dim3(8, 40), 256, 0, stream>>>(AL, GT, SA + 512);
    k_iv<<<2, 256, 0, stream>>>(iv, out, SA);

    // 5-level Hillis-Steele boundary scan (bases M8T, M16T, M32T, M64T, M128T)
    dim3 gscan(8, 40);
    k_scan<<<gscan, 256, 0, stream>>>(SA, SB, MP + 7 * (size_t)MSZ, 1);
    k_scan<<<gscan, 256, 0, stream>>>(SB, SA, SQ, 2);
    k_scan<<<gscan, 256, 0, stream>>>(SA, SB, SQ + MSZ, 4);
    k_scan<<<gscan, 256, 0, stream>>>(SB, SA, SQ + 2 * (size_t)MSZ, 8);
    k_scan<<<gscan, 256, 0, stream>>>(SA, SB, SQ + 3 * (size_t)MSZ, 16);

    // final: out[8k+j+1] = SS[k] @ M^{j+1}T + alphahat_k @ FJ_j
    k_final<<<dim3(64, 40), 256, 0, stream>>>(SB, MP, AL, FJ, out);
}

// Round 5
// 560.578 us; speedup vs baseline: 3.2608x; 1.3502x over previous
//
#include <hip/hip_runtime.h>

#define TT    20000
#define CCH   2500        // TT / 8
#define RROWS 2501
#define NDATA 2000
#define MSZ   262144      // 512*512

// workspace layout (floats) — 23.9 MB total (round-2-proven budget)
static constexpr size_t OFF_HT  = 0;                   // HT = (30A)^T ; later reused for M32T
static constexpr size_t OFF_H2T = (size_t)MSZ;         // H^2 T        ; later reused for M16T
static constexpr size_t OFF_MP  = 2*(size_t)MSZ;       // M1T..M8T
static constexpr size_t OFF_SQ  = 10*(size_t)MSZ;      // M64T, M128T
static constexpr size_t OFF_VEC = 12*(size_t)MSZ;      // v,w1,w2,w3,g,c,u1,u2 (8x512)
static constexpr size_t OFF_FJ  = OFF_VEC + 4096;      // 8 x 40 x 512
static constexpr size_t OFF_AL  = OFF_FJ + 163840;     // 20000 x 5
static constexpr size_t OFF_SA  = OFF_AL + 102400;     // 2501 x 512
static constexpr size_t OFF_SB  = OFF_SA + (size_t)RROWS*512;

#define MICRO_FMA(a, b) do { \
  acc0.x += (a).x*(b).x; acc0.y += (a).x*(b).y; acc0.z += (a).x*(b).z; acc0.w += (a).x*(b).w; \
  acc1.x += (a).y*(b).x; acc1.y += (a).y*(b).y; acc1.z += (a).y*(b).z; acc1.w += (a).y*(b).w; \
  acc2.x += (a).z*(b).x; acc2.y += (a).z*(b).y; acc2.z += (a).z*(b).z; acc2.w += (a).z*(b).w; \
  acc3.x += (a).w*(b).x; acc3.y += (a).w*(b).y; acc3.z += (a).w*(b).z; acc3.w += (a).w*(b).w; \
} while (0)

#define DECL_GEMM_VARS() \
    int t = threadIdx.x; \
    int tx = t & 15, ty = t >> 4; \
    int ar = t & 63, ak4 = (t >> 6) * 4; \
    int bk = t >> 4, bc4 = (t & 15) * 4; \
    float4 acc0 = {0,0,0,0}, acc1 = {0,0,0,0}, acc2 = {0,0,0,0}, acc3 = {0,0,0,0}; \
    (void)tx; (void)ty; (void)ar; (void)ak4; (void)bk; (void)bc4

// double-buffered 64x64x512 K-loop: regs-prefetch, ONE sync per iter
#define GEMM_CORE(LOADA, LOADB) \
    { float4 ra = LOADA(0); float4 rbv = LOADB(0); \
    As[0][ak4+0][ar]=ra.x; As[0][ak4+1][ar]=ra.y; As[0][ak4+2][ar]=ra.z; As[0][ak4+3][ar]=ra.w; \
    *(float4*)&Bs[0][bk][bc4] = rbv; \
    for (int kt = 1; kt <= 32; kt++) { \
        __syncthreads(); \
        const int cur = (kt - 1) & 1; \
        if (kt < 32) { ra = LOADA(kt); rbv = LOADB(kt); } \
        _Pragma("unroll") \
        for (int kk = 0; kk < 16; kk++) { \
            float4 a = *(const float4*)&As[cur][kk][ty*4]; \
            float4 b = *(const float4*)&Bs[cur][kk][tx*4]; \
            MICRO_FMA(a, b); \
        } \
        if (kt < 32) { const int nb = kt & 1; \
            As[nb][ak4+0][ar]=ra.x; As[nb][ak4+1][ar]=ra.y; As[nb][ak4+2][ar]=ra.z; As[nb][ak4+3][ar]=ra.w; \
            *(float4*)&Bs[nb][bk][bc4] = rbv; } \
    } }

// Z = A @ B, one 64x64 tile (idx: 8x8)
__device__ __forceinline__ void pow_tile(const float* __restrict__ Ap,
                                         const float* __restrict__ Bp,
                                         float* __restrict__ Zp, int idx) {
    __shared__ float As[2][16][68], Bs[2][16][68];
    DECL_GEMM_VARS();
    int rb = (idx >> 3) * 64, cb = (idx & 7) * 64;
#define LA(kt) (*(const float4*)&Ap[(size_t)(rb+ar)*512 + (kt)*16 + ak4])
#define LB(kt) (*(const float4*)&Bp[(size_t)((kt)*16+bk)*512 + cb + bc4])
    GEMM_CORE(LA, LB)
#undef LA
#undef LB
    size_t zb = (size_t)(rb + ty*4)*512 + cb + tx*4;
    *(float4*)&Zp[zb]        = acc0;
    *(float4*)&Zp[zb + 512]  = acc1;
    *(float4*)&Zp[zb + 1024] = acc2;
    *(float4*)&Zp[zb + 1536] = acc3;
}

// y[rb..rb+128) = H^T-style matvec: y[r] = sum_k MT[k,r] x[k]; optional g-combine
__device__ __forceinline__ void matvecT128(const float* __restrict__ MT,
                                           const float* __restrict__ x,
                                           float* __restrict__ y, int rb,
                                           const float* __restrict__ gc,
                                           const float* __restrict__ gu1,
                                           const float* __restrict__ gu2) {
    __shared__ float xs[512];
    __shared__ float red2[2][128];
    int t = threadIdx.x;
    xs[t] = x[t]; xs[t + 256] = x[t + 256];
    __syncthreads();
    int rl = t & 127, h = t >> 7;
    size_t col = (size_t)rb + rl;
    float acc = 0.f;
    int k0 = h << 8;
    #pragma unroll 4
    for (int k = k0; k < k0 + 256; k++) acc += MT[(size_t)k*512 + col] * xs[k];
    red2[h][rl] = acc;
    __syncthreads();
    if (t < 128) {
        float s = red2[0][t] + red2[1][t];
        int r = rb + t;
        if (gc) y[r] = 30.f * (gc[r] + 0.5f*gu1[r] + (1.f/6.f)*gu2[r] + (1.f/24.f)*s);
        else    y[r] = s;
    }
}

__device__ __forceinline__ float interp1(float tt, const float* __restrict__ xp,
                                         const float* __restrict__ fp) {
    if (tt <= xp[0]) return fp[0];
    if (tt >= xp[NDATA-1]) return fp[NDATA-1];
    int lo = 0, hi = NDATA - 1;
    while (hi - lo > 1) { int mid = (lo + hi) >> 1; if (xp[mid] <= tt) lo = mid; else hi = mid; }
    float x0 = xp[lo], x1 = xp[lo+1];
    return fp[lo] + (fp[lo+1] - fp[lo]) * (tt - x0) / (x1 - x0);
}

// stage 1: HT=(30A)^T transpose (256 blks) + v,c (1) + out0/SA0 (1) + alphas (79)
__global__ __launch_bounds__(256) void k_setup(const float* __restrict__ A,
        const float* __restrict__ B, const float* __restrict__ Q,
        const float* __restrict__ te, const float* __restrict__ Tt,
        const float* __restrict__ Tv, const float* __restrict__ iv,
        float* __restrict__ HT, float* __restrict__ vec, float* __restrict__ AL,
        float* __restrict__ out, float* __restrict__ SA) {
    int bx = blockIdx.x, t = threadIdx.x;
    if (bx < 256) {
        __shared__ float Ts[32][33];
        int tr = bx >> 4, tc = bx & 15;
        int rl = t >> 3, cl4 = (t & 7) * 4;
        float4 a = *(const float4*)&A[(size_t)(tr*32 + rl)*512 + tc*32 + cl4];
        Ts[rl][cl4+0] = 30.f*a.x; Ts[rl][cl4+1] = 30.f*a.y;
        Ts[rl][cl4+2] = 30.f*a.z; Ts[rl][cl4+3] = 30.f*a.w;
        __syncthreads();
        float4 o;
        o.x = Ts[cl4+0][rl]; o.y = Ts[cl4+1][rl]; o.z = Ts[cl4+2][rl]; o.w = Ts[cl4+3][rl];
        *(float4*)&HT[(size_t)(tc*32 + rl)*512 + tr*32 + cl4] = o;
    } else if (bx == 256) {
        for (int i = t; i < 512; i += 256) {
            float v = B[i*9];
            float c = 0.f;
            #pragma unroll
            for (int j = 0; j < 8; j++) c += B[i*9 + 1 + j] * Q[j];
            vec[i] = v;          // v
            vec[2560 + i] = c;   // c
        }
    } else if (bx == 257) {
        for (int i = t; i < 512; i += 256) { out[i] = iv[i]; SA[i] = iv[i]; }
    } else {
        int n = (bx - 258) * 256 + t;
        if (n >= TT) return;
        float* a = AL + (size_t)n * 5;
        if (n == TT - 1) { a[0]=a[1]=a[2]=a[3]=a[4]=0.f; return; }  // padding step
        float tt = te[n];
        float T1 = interp1(tt, Tt, Tv);
        float T2 = interp1(tt + 10.f, Tt, Tv);
        float T3 = interp1(tt + 20.f, Tt, Tv);
        float T4 = interp1(tt + 30.f, Tt, Tv);
        a[0] = 3.75f * (T1 + 3.f*T2 + 3.f*T3 + T4);
        a[1] = 3.75f * (T1 + 2.f*T2 + T3);
        a[2] = 3.75f * (T1*(1.f/3.f) + T2);
        a[3] = 1.25f * T1;
        a[4] = 1.f;
    }
}

// stage 2: H2T = HT@HT  +  kv1 (w1=Hv, u1=Hc)
__global__ __launch_bounds__(256) void k_h2kv(const float* __restrict__ HT,
                                              float* __restrict__ H2T,
                                              float* __restrict__ vec) {
    int bx = blockIdx.x;
    if (bx < 64) { pow_tile(HT, HT, H2T, bx); return; }
    int sub = bx - 64, which = sub >> 2, rb = (sub & 3) * 128;
    if (which == 0) matvecT128(HT, vec,        vec + 512,  rb, 0, 0, 0);   // w1
    else            matvecT128(HT, vec + 2560, vec + 3072, rb, 0, 0, 0);   // u1
}

// stage 3: M1T = I + HT + CT@H2T (CT = I/2 + HT/6 + H2T/24, built on the fly) + kv2
__global__ __launch_bounds__(256) void k_m1kv(const float* __restrict__ HT,
                                              const float* __restrict__ H2T,
                                              float* __restrict__ M1T,
                                              float* __restrict__ vec) {
    int bx = blockIdx.x;
    if (bx < 64) {
        __shared__ float As[2][16][68], Bs[2][16][68];
        DECL_GEMM_VARS();
        int rb = (bx >> 3) * 64, cb = (bx & 7) * 64;
#define LA(kt) ({ size_t off = (size_t)(rb+ar)*512 + (kt)*16 + ak4; \
        float4 h  = *(const float4*)&HT[off]; \
        float4 h2 = *(const float4*)&H2T[off]; \
        float4 r_; \
        r_.x = h.x*(1.f/6.f) + h2.x*(1.f/24.f); r_.y = h.y*(1.f/6.f) + h2.y*(1.f/24.f); \
        r_.z = h.z*(1.f/6.f) + h2.z*(1.f/24.f); r_.w = h.w*(1.f/6.f) + h2.w*(1.f/24.f); \
        int dd = (rb+ar) - ((kt)*16 + ak4); \
        if (dd >= 0 && dd < 4) (&r_.x)[dd] += 0.5f; \
        r_; })
#define LB(kt) (*(const float4*)&H2T[(size_t)((kt)*16+bk)*512 + cb + bc4])
        GEMM_CORE(LA, LB)
#undef LA
#undef LB
        int col = cb + tx*4;
        #pragma unroll
        for (int i = 0; i < 4; i++) {
            int r = rb + ty*4 + i;
            float4 h = *(const float4*)&HT[(size_t)r*512 + col];
            float4* ac = (i==0) ? &acc0 : (i==1) ? &acc1 : (i==2) ? &acc2 : &acc3;
            ac->x += h.x + (r == col+0 ? 1.f : 0.f);
            ac->y += h.y + (r == col+1 ? 1.f : 0.f);
            ac->z += h.z + (r == col+2 ? 1.f : 0.f);
            ac->w += h.w + (r == col+3 ? 1.f : 0.f);
            *(float4*)&M1T[(size_t)r*512 + col] = *ac;
        }
        return;
    }
    int sub = bx - 64, which = sub >> 2, rb = (sub & 3) * 128;
    if (which == 0) matvecT128(HT, vec + 512,  vec + 1024, rb, 0, 0, 0);   // w2
    else            matvecT128(HT, vec + 3072, vec + 3584, rb, 0, 0, 0);   // u2
}

// stage 4: M2T = M1T@M1T + kv3 (w3; u3->g)
__global__ __launch_bounds__(256) void k_m2kv(const float* __restrict__ M1T,
                                              float* __restrict__ M2T,
                                              const float* __restrict__ HT,
                                              float* __restrict__ vec) {
    int bx = blockIdx.x;
    if (bx < 64) { pow_tile(M1T, M1T, M2T, bx); return; }
    int sub = bx - 64, which = sub >> 2, rb = (sub & 3) * 128;
    if (which == 0) matvecT128(HT, vec + 1024, vec + 1536, rb, 0, 0, 0);   // w3
    else matvecT128(HT, vec + 3584, vec + 2048, rb,                         // g (u3 in-flight)
                    vec + 2560, vec + 3072, vec + 3584);
}

// stages 5/6: batched Z_sel = A @ B_sel
__global__ __launch_bounds__(256) void k_pow(const float* __restrict__ A,
                                             const float* __restrict__ B0,
                                             float* __restrict__ Z0) {
    int sel = blockIdx.x >> 6;
    pow_tile(A, B0 + (size_t)sel*MSZ, Z0 + (size_t)sel*MSZ, blockIdx.x & 63);
}

// stage 7: wgen -> FJ directly (all 8 diagonals incl. zeros)  +  SQ: M16 = M8^2
__global__ __launch_bounds__(256) void k_wgen_sq(const float* __restrict__ vec,
                                                 const float* __restrict__ MP,
                                                 float* __restrict__ FJ,
                                                 const float* __restrict__ P,
                                                 float* __restrict__ Pout) {
    int bx = blockIdx.x;
    if (bx >= 64) { pow_tile(P, P, Pout, bx - 64); return; }
    int d = bx >> 3, cb = (bx & 7) * 64;
    int t = threadIdx.x;
    if (d == 0) {
        for (int idx = t; idx < 320; idx += 256) {
            int r = idx >> 6, c = idx & 63;
            float s = vec[(size_t)r*512 + cb + c];
            #pragma unroll
            for (int i = 0; i < 8; i++)
                FJ[((size_t)i*40 + i*5 + r)*512 + cb + c] = s;
        }
        for (int j = 0; j < 7; j++)
            for (int i = j + 1; i < 8; i++)
                for (int idx = t; idx < 320; idx += 256) {
                    int r = idx >> 6, c = idx & 63;
                    FJ[((size_t)j*40 + i*5 + r)*512 + cb + c] = 0.f;
                }
        return;
    }
    __shared__ float Ws[5][512];
    __shared__ float red4[4][5][64];
    const float* Mj = MP + (size_t)(d - 1)*MSZ;
    for (int e = t; e < 2560; e += 256) Ws[e >> 9][e & 511] = vec[e];
    __syncthreads();
    int col = t & 63, kq = t >> 6, k0 = kq * 128;
    float acc[5] = {0.f, 0.f, 0.f, 0.f, 0.f};
    #pragma unroll 4
    for (int k = k0; k < k0 + 128; k++) {
        float m = Mj[(size_t)k*512 + cb + col];
        acc[0] += Ws[0][k]*m; acc[1] += Ws[1][k]*m; acc[2] += Ws[2][k]*m;
        acc[3] += Ws[3][k]*m; acc[4] += Ws[4][k]*m;
    }
    #pragma unroll
    for (int r = 0; r < 5; r++) red4[kq][r][col] = acc[r];
    __syncthreads();
    for (int idx = t; idx < 320; idx += 256) {
        int r = idx >> 6, c = idx & 63;
        float s = red4[0][r][c] + red4[1][r][c] + red4[2][r][c] + red4[3][r][c];
        for (int i = 0; i + d < 8; i++)
            FJ[((size_t)(i + d)*40 + i*5 + r)*512 + cb + c] = s;
    }
}

// stage 8: E = ALhat(2500x40) @ GT(=FJ[7]) -> SA rows 1..2500  +  SQ: M32 = M16^2
__global__ __launch_bounds__(256) void k_e40_sq(const float* __restrict__ AL,
                                                const float* __restrict__ FJ,
                                                float* __restrict__ SA1,
                                                const float* __restrict__ P,
                                                float* __restrict__ Pout) {
    int bx = blockIdx.x;
    if (bx >= 320) { pow_tile(P, P, Pout, bx - 320); return; }
    const float* GT = FJ + (size_t)7*40*512;
    int kb = (bx >> 3) * 64, cb = (bx & 7) * 64;
    __shared__ float Ah[64][41], Bsv[40][68];
    int t = threadIdx.x;
    int tx = t & 15, ty = t >> 4;
    #pragma unroll
    for (int m = 0; m < 10; m++) {
        int e = t + 256*m;
        int row = e / 40, q = e - 40*row;
        float v = 0.f;
        if (kb + row < CCH) v = AL[(size_t)(kb + row)*40 + q];
        Ah[row][q] = v;
        int fq = e >> 6, fc = e & 63;
        Bsv[fq][fc] = GT[(size_t)fq*512 + cb + fc];
    }
    __syncthreads();
    float4 acc0 = {0,0,0,0}, acc1 = {0,0,0,0}, acc2 = {0,0,0,0}, acc3 = {0,0,0,0};
    #pragma unroll 8
    for (int q = 0; q < 40; q++) {
        float4 b = *(const float4*)&Bsv[q][tx*4];
        float a0 = Ah[ty*4+0][q], a1 = Ah[ty*4+1][q];
        float a2 = Ah[ty*4+2][q], a3 = Ah[ty*4+3][q];
        acc0.x += a0*b.x; acc0.y += a0*b.y; acc0.z += a0*b.z; acc0.w += a0*b.w;
        acc1.x += a1*b.x; acc1.y += a1*b.y; acc1.z += a1*b.z; acc1.w += a1*b.w;
        acc2.x += a2*b.x; acc2.y += a2*b.y; acc2.z += a2*b.z; acc2.w += a2*b.w;
        acc3.x += a3*b.x; acc3.y += a3*b.y; acc3.z += a3*b.z; acc3.w += a3*b.w;
    }
    int col = cb + tx*4;
    #pragma unroll
    for (int i = 0; i < 4; i++) {
        int k = kb + ty*4 + i;
        if (k < CCH) {
            float4 a = (i==0) ? acc0 : (i==1) ? acc1 : (i==2) ? acc2 : acc3;
            *(float4*)&SA1[(size_t)k*512 + col] = a;
        }
    }
}

// stages 9..13: scan level (Aout[k] = Ain[k] + Ain[k-shift]@QT)  + optional SQ
__global__ __launch_bounds__(256) void k_scan_sq(const float* __restrict__ Ain,
                                                 float* __restrict__ Aout,
                                                 const float* __restrict__ QT, int shift,
                                                 const float* __restrict__ P,
                                                 float* __restrict__ Pout) {
    int bx = blockIdx.x;
    if (bx >= 320) { pow_tile(P, P, Pout, bx - 320); return; }
    __shared__ float As[2][16][68], Bs[2][16][68];
    DECL_GEMM_VARS();
    int kb = (bx >> 3) * 64, cb = (bx & 7) * 64;
    int xr = kb + ar - shift;
    bool aval = (xr >= 0) && (kb + ar < RROWS);
#define LA(kt) ({ float4 z = {0,0,0,0}; \
        if (aval) z = *(const float4*)&Ain[(size_t)xr*512 + (kt)*16 + ak4]; z; })
#define LB(kt) (*(const float4*)&QT[(size_t)((kt)*16+bk)*512 + cb + bc4])
    GEMM_CORE(LA, LB)
#undef LA
#undef LB
    int col = cb + tx*4;
    #pragma unroll
    for (int i = 0; i < 4; i++) {
        int krow = kb + ty*4 + i;
        if (krow < RROWS) {
            float4 own = *(const float4*)&Ain[(size_t)krow*512 + col];
            float4 a = (i==0) ? acc0 : (i==1) ? acc1 : (i==2) ? acc2 : acc3;
            float4 res = {own.x + a.x, own.y + a.y, own.z + a.z, own.w + a.w};
            *(float4*)&Aout[(size_t)krow*512 + col] = res;
        }
    }
}

// stage 14: out[8k+j+1] = SS[k] @ M^{j+1}T + ALhat_k @ FJ_j
__global__ __launch_bounds__(256) void k_final(const float* __restrict__ SS,
                                               const float* __restrict__ MP,
                                               const float* __restrict__ AL,
                                               const float* __restrict__ FJ,
                                               float* __restrict__ out) {
    __shared__ float As[2][16][68], Bs[2][16][68];
    __shared__ float Ah[64][41], Fs[40][68];
    DECL_GEMM_VARS();
    int j = blockIdx.x >> 3;
    const float* Bm = MP + (size_t)j*MSZ;
    int cb = (blockIdx.x & 7) * 64;
    int kb = blockIdx.y * 64;
    bool aval = (kb + ar < CCH);
#define LA(kt) ({ float4 z = {0,0,0,0}; \
        if (aval) z = *(const float4*)&SS[(size_t)(kb+ar)*512 + (kt)*16 + ak4]; z; })
#define LB(kt) (*(const float4*)&Bm[(size_t)((kt)*16+bk)*512 + cb + bc4])
    GEMM_CORE(LA, LB)
#undef LA
#undef LB
    // rank-40 forcing epilogue
    #pragma unroll
    for (int m = 0; m < 10; m++) {
        int e = t + 256*m;
        int row = e / 40, q = e - 40*row;
        float v = 0.f;
        if (kb + row < CCH) v = AL[(size_t)(kb + row)*40 + q];
        Ah[row][q] = v;
        int fq = e >> 6, fc = e & 63;
        Fs[fq][fc] = FJ[(size_t)j*40*512 + (size_t)fq*512 + cb + fc];
    }
    __syncthreads();
    #pragma unroll 8
    for (int q = 0; q < 40; q++) {
        float4 b = *(const float4*)&Fs[q][tx*4];
        float a0 = Ah[ty*4+0][q], a1 = Ah[ty*4+1][q];
        float a2 = Ah[ty*4+2][q], a3 = Ah[ty*4+3][q];
        acc0.x += a0*b.x; acc0.y += a0*b.y; acc0.z += a0*b.z; acc0.w += a0*b.w;
        acc1.x += a1*b.x; acc1.y += a1*b.y; acc1.z += a1*b.z; acc1.w += a1*b.w;
        acc2.x += a2*b.x; acc2.y += a2*b.y; acc2.z += a2*b.z; acc2.w += a2*b.w;
        acc3.x += a3*b.x; acc3.y += a3*b.y; acc3.z += a3*b.z; acc3.w += a3*b.w;
    }
    int col = cb + tx*4;
    #pragma unroll
    for (int i = 0; i < 4; i++) {
        int k = kb + ty*4 + i;
        int n = 8*k + j + 1;
        if (k < CCH && n < TT) {
            float4 a = (i==0) ? acc0 : (i==1) ? acc1 : (i==2) ? acc2 : acc3;
            *(float4*)&out[(size_t)n*512 + col] = a;
        }
    }
}

extern "C" void kernel_launch(void* const* d_in, const int* in_sizes, int n_in,
                              void* d_out, int out_size, void* d_ws, size_t ws_size,
                              hipStream_t stream) {
    const float* A  = (const float*)d_in[0];
    const float* B  = (const float*)d_in[1];
    const float* Q  = (const float*)d_in[2];
    const float* Tt = (const float*)d_in[3];
    const float* Tv = (const float*)d_in[4];
    const float* iv = (const float*)d_in[5];
    const float* te = (const float*)d_in[6];
    float* out = (float*)d_out;
    float* w = (float*)d_ws;

    float* HT  = w + OFF_HT;
    float* H2T = w + OFF_H2T;
    float* MP  = w + OFF_MP;
    float* SQ  = w + OFF_SQ;
    float* vec = w + OFF_VEC;
    float* FJ  = w + OFF_FJ;
    float* AL  = w + OFF_AL;
    float* SA  = w + OFF_SA;
    float* SB  = w + OFF_SB;

    float* M16  = H2T;          // reuse (H2T dead after stage 3)
    float* M32  = HT;           // reuse (HT dead after stage 4)
    float* M64  = SQ;
    float* M128 = SQ + MSZ;
    float* M8   = MP + 7*(size_t)MSZ;

    // 1. setup: HT, v/c, out row0 + SA row0, alphas
    k_setup<<<337, 256, 0, stream>>>(A, B, Q, te, Tt, Tv, iv, HT, vec, AL, out, SA);
    // 2. H2T + (w1,u1)
    k_h2kv<<<72, 256, 0, stream>>>(HT, H2T, vec);
    // 3. M1T + (w2,u2)
    k_m1kv<<<72, 256, 0, stream>>>(HT, H2T, MP, vec);
    // 4. M2T + (w3, g)
    k_m2kv<<<72, 256, 0, stream>>>(MP, MP + MSZ, HT, vec);
    // 5. [M3T,M4T] = M2T @ [M1T,M2T]
    k_pow<<<128, 256, 0, stream>>>(MP + MSZ, MP, MP + 2*(size_t)MSZ);
    // 6. [M5..M8]T = M4T @ [M1..M4]T
    k_pow<<<256, 256, 0, stream>>>(MP + 3*(size_t)MSZ, MP, MP + 4*(size_t)MSZ);
    // 7. FJ (wgen direct) + M16
    k_wgen_sq<<<128, 256, 0, stream>>>(vec, MP, FJ, M8, M16);
    // 8. E -> SA rows 1.. + M32
    k_e40_sq<<<384, 256, 0, stream>>>(AL, FJ, SA + 512, M16, M32);
    // 9..13. scan levels (+ M64, M128)
    k_scan_sq<<<384, 256, 0, stream>>>(SA, SB, M8,   1,  M32, M64);
    k_scan_sq<<<384, 256, 0, stream>>>(SB, SA, M16,  2,  M64, M128);
    k_scan_sq<<<320, 256, 0, stream>>>(SA, SB, M32,  4,  nullptr, nullptr);
    k_scan_sq<<<320, 256, 0, stream>>>(SB, SA, M64,  8,  nullptr, nullptr);
    k_scan_sq<<<320, 256, 0, stream>>>(SA, SB, M128, 16, nullptr, nullptr);
    // 14. final
    k_final<<<dim3(64, 40), 256, 0, stream>>>(SB, MP, AL, FJ, out);
}